// Round 2
// baseline (1094.464 us; speedup 1.0000x reference)
//
#include <hip/hip_runtime.h>
#include <math.h>

namespace {
constexpr int NB   = 16;
constexpr int NC   = 684;
constexpr int NH   = 32;
constexpr int NW   = 128;
constexpr int NHID = 256;
constexpr int NA   = 512;
constexpr int HW   = NH * NW;  // 4096
}

__device__ __forceinline__ float fast_tanh(float x) {
  float e = __expf(2.0f * x);
  return 1.0f - 2.0f / (e + 1.0f);
}

// query[b,a] = b_hidden[a] + hidden[b,:] . W_hidden[a,:]
__global__ __launch_bounds__(512) void query_kernel(
    const float* __restrict__ hidden, const float* __restrict__ Wh,
    const float* __restrict__ bh, float* __restrict__ q) {
  const int b = blockIdx.x, a = threadIdx.x;
  const float4* h4 = reinterpret_cast<const float4*>(hidden + b * NHID);
  const float4* w4 = reinterpret_cast<const float4*>(Wh + (size_t)a * NHID);
  float s = bh[a];
  #pragma unroll 8
  for (int k = 0; k < NHID / 4; ++k) {
    float4 hv = h4[k], wv = w4[k];
    s = fmaf(hv.x, wv.x, s); s = fmaf(hv.y, wv.y, s);
    s = fmaf(hv.z, wv.z, s); s = fmaf(hv.w, wv.w, s);
  }
  q[b * NA + a] = s;
}

// M[a][dy*12+dx] = sum_k W_attn[a,k] * Wc[k, dy*11+dx]   (dx==11 is zero pad)
__global__ __launch_bounds__(192) void m_kernel(
    const float* __restrict__ Wattn, const float* __restrict__ Wc,
    float* __restrict__ M) {
  const int a = blockIdx.x, t = threadIdx.x;
  if (t >= 132) return;
  const int dy = t / 12, dx = t % 12;
  float s = 0.0f;
  if (dx < 11) {
    const int j = dy * 11 + dx;
    const float* wa = Wattn + (size_t)a * 512;
    for (int k = 0; k < 512; ++k) s = fmaf(wa[k], Wc[k * 121 + j], s);
  }
  M[(size_t)a * 132 + t] = s;
}

// Partial energy over one a-half (256 a's).
__global__ __launch_bounds__(256) void energy_kernel(
    const float* __restrict__ cft,   // [B,A,H,W]
    const float* __restrict__ cmt,   // [B,H,W,A]
    const float* __restrict__ asum,  // [B,1,H,W]
    const float* __restrict__ q,     // [B,A]
    const float* __restrict__ M,     // [A,132]
    const float* __restrict__ walpha,// [A]
    float* __restrict__ epart0,      // [B,H*W] half 0
    float* __restrict__ epart1)      // [B,H*W] half 1
{
  const int blk  = blockIdx.x;       // B*H*2 = 1024
  const int half = blk & 1;
  const int bh   = blk >> 1;
  const int b    = bh >> 5;
  const int h    = bh & 31;
  const int tid  = threadIdx.x;
  const int lane = tid & 63;
  const int wave = __builtin_amdgcn_readfirstlane(tid >> 6);  // 0..3

  __shared__ float asum_lds[11][144];
  __shared__ float part[4][NW];

  for (int i = tid; i < 11 * 144; i += 256) {
    const int r = i / 144, cc = i % 144;
    const int y = h + r - 5, x = cc - 5;
    float v = 0.0f;
    if (y >= 0 && y < NH && x >= 0 && x < NW) v = asum[(b * NH + y) * NW + x];
    asum_lds[r][cc] = v;
  }
  __syncthreads();

  const int w0 = lane, w1 = lane + 64;
  const int abase = half * 256 + wave * 64;
  const float* q_b = q + b * NA;
  const float* cmt_row0 = cmt + (size_t)((b * NH + h) * NW + w0) * NA;
  const float* cmt_row1 = cmt + (size_t)((b * NH + h) * NW + w1) * NA;

  float acc0 = 0.0f, acc1 = 0.0f;

  for (int ab = 0; ab < 8; ++ab) {
    const int a8 = abase + ab * 8;

    // prefetch cmt / cft into registers; latency hides under the conv FMAs
    const float4 cma0 = *reinterpret_cast<const float4*>(cmt_row0 + a8);
    const float4 cma1 = *reinterpret_cast<const float4*>(cmt_row0 + a8 + 4);
    const float4 cmb0 = *reinterpret_cast<const float4*>(cmt_row1 + a8);
    const float4 cmb1 = *reinterpret_cast<const float4*>(cmt_row1 + a8 + 4);
    float cf0[8], cf1[8];
    #pragma unroll
    for (int ai = 0; ai < 8; ++ai) {
      const float* cr = cft + ((size_t)(b * NA + a8 + ai) * NH + h) * NW;
      cf0[ai] = cr[w0];
      cf1[ai] = cr[w1];
    }

    float cov0[8], cov1[8];
    #pragma unroll
    for (int i = 0; i < 8; ++i) { cov0[i] = 0.0f; cov1[i] = 0.0f; }

    #pragma unroll
    for (int dy = 0; dy < 11; ++dy) {
      float p0[11], p1[11];
      #pragma unroll
      for (int dx = 0; dx < 11; ++dx) {
        p0[dx] = asum_lds[dy][w0 + dx];
        p1[dx] = asum_lds[dy][w1 + dx];
      }
      #pragma unroll
      for (int ai = 0; ai < 8; ++ai) {
        const float4* mr = reinterpret_cast<const float4*>(
            M + (size_t)(a8 + ai) * 132 + dy * 12);
        const float4 m0 = mr[0];
        const float4 m1 = mr[1];
        const float4 m2 = mr[2];
        float c0 = cov0[ai], c1 = cov1[ai];
        c0 = fmaf(p0[0], m0.x, c0);  c1 = fmaf(p1[0], m0.x, c1);
        c0 = fmaf(p0[1], m0.y, c0);  c1 = fmaf(p1[1], m0.y, c1);
        c0 = fmaf(p0[2], m0.z, c0);  c1 = fmaf(p1[2], m0.z, c1);
        c0 = fmaf(p0[3], m0.w, c0);  c1 = fmaf(p1[3], m0.w, c1);
        c0 = fmaf(p0[4], m1.x, c0);  c1 = fmaf(p1[4], m1.x, c1);
        c0 = fmaf(p0[5], m1.y, c0);  c1 = fmaf(p1[5], m1.y, c1);
        c0 = fmaf(p0[6], m1.z, c0);  c1 = fmaf(p1[6], m1.z, c1);
        c0 = fmaf(p0[7], m1.w, c0);  c1 = fmaf(p1[7], m1.w, c1);
        c0 = fmaf(p0[8], m2.x, c0);  c1 = fmaf(p1[8], m2.x, c1);
        c0 = fmaf(p0[9], m2.y, c0);  c1 = fmaf(p1[9], m2.y, c1);
        c0 = fmaf(p0[10], m2.z, c0); c1 = fmaf(p1[10], m2.z, c1);
        cov0[ai] = c0; cov1[ai] = c1;
      }
    }

    const float cm0[8] = {cma0.x, cma0.y, cma0.z, cma0.w,
                          cma1.x, cma1.y, cma1.z, cma1.w};
    const float cm1[8] = {cmb0.x, cmb0.y, cmb0.z, cmb0.w,
                          cmb1.x, cmb1.y, cmb1.z, cmb1.w};
    #pragma unroll
    for (int ai = 0; ai < 8; ++ai) {
      const int a = a8 + ai;
      const float qa = q_b[a];
      const float wa = walpha[a];
      const float e0 = qa + cov0[ai] + cf0[ai] + cm0[ai];
      const float e1 = qa + cov1[ai] + cf1[ai] + cm1[ai];
      acc0 = fmaf(wa, fast_tanh(e0), acc0);
      acc1 = fmaf(wa, fast_tanh(e1), acc1);
    }
  }

  part[wave][w0] = acc0;
  part[wave][w1] = acc1;
  __syncthreads();
  float* epart = half ? epart1 : epart0;
  if (tid < NW) {
    epart[(b * NH + h) * NW + tid] =
        part[0][tid] + part[1][tid] + part[2][tid] + part[3][tid];
  }
}

// per-b softmax over 4096 (mask-aware): e = epart0 + epart1
__global__ __launch_bounds__(256) void softmax_kernel(
    float* __restrict__ epart0_alpha,      // [B,4096] in (half 0), alpha out
    const float* __restrict__ epart1,      // [B,4096] (half 1)
    const int* __restrict__ mask,          // [B,4096]
    const float* __restrict__ asum,        // [B,4096]
    float* __restrict__ asum_new)          // [B,4096]
{
  const int b = blockIdx.x, tid = threadIdx.x;
  const int base = b * HW;
  __shared__ float redm[4];
  __shared__ float reds[4];

  float ev[16];
  bool mv[16];
  float mx = -1e30f;
  #pragma unroll
  for (int k = 0; k < 16; ++k) {
    const int i = base + tid + k * 256;
    ev[k] = epart0_alpha[i] + epart1[i];
    mv[k] = mask[i] != 0;
    mx = fmaxf(mx, mv[k] ? ev[k] : -1e30f);
  }
  #pragma unroll
  for (int o = 32; o > 0; o >>= 1) mx = fmaxf(mx, __shfl_down(mx, o));
  if ((tid & 63) == 0) redm[tid >> 6] = mx;
  __syncthreads();
  mx = fmaxf(fmaxf(redm[0], redm[1]), fmaxf(redm[2], redm[3]));

  float s = 0.0f;
  float pv[16];
  #pragma unroll
  for (int k = 0; k < 16; ++k) {
    pv[k] = mv[k] ? expf(ev[k] - mx) : 0.0f;
    s += pv[k];
  }
  #pragma unroll
  for (int o = 32; o > 0; o >>= 1) s += __shfl_down(s, o);
  if ((tid & 63) == 0) reds[tid >> 6] = s;
  __syncthreads();
  s = reds[0] + reds[1] + reds[2] + reds[3];
  const float inv = 1.0f / s;

  #pragma unroll
  for (int k = 0; k < 16; ++k) {
    const int i = base + tid + k * 256;
    const float a = pv[k] * inv;
    epart0_alpha[i] = a;
    asum_new[i] = a + asum[i];
  }
}

// context[b,c] = sum_i alpha[b,i] * cnn[b,c,i]
__global__ __launch_bounds__(256) void context_kernel(
    const float* __restrict__ cnn, const float* __restrict__ alpha,
    float* __restrict__ out) {
  const int blk = blockIdx.x;            // NB*NC
  const int b = blk / NC, c = blk - b * NC;
  const float4* crow = reinterpret_cast<const float4*>(cnn + (size_t)(b * NC + c) * HW);
  const float4* arow = reinterpret_cast<const float4*>(alpha + (size_t)b * HW);
  const int tid = threadIdx.x;
  float s = 0.0f;
  #pragma unroll
  for (int i = tid; i < HW / 4; i += 256) {
    const float4 cv = crow[i];
    const float4 av = arow[i];
    s = fmaf(cv.x, av.x, s); s = fmaf(cv.y, av.y, s);
    s = fmaf(cv.z, av.z, s); s = fmaf(cv.w, av.w, s);
  }
  #pragma unroll
  for (int o = 32; o > 0; o >>= 1) s += __shfl_down(s, o);
  __shared__ float red[4];
  if ((tid & 63) == 0) red[tid >> 6] = s;
  __syncthreads();
  if (tid == 0) out[blk] = red[0] + red[1] + red[2] + red[3];
}

extern "C" void kernel_launch(void* const* d_in, const int* in_sizes, int n_in,
                              void* d_out, int out_size, void* d_ws, size_t ws_size,
                              hipStream_t stream) {
  const float* cnn    = (const float*)d_in[0];
  const float* cft    = (const float*)d_in[1];
  const float* hidden = (const float*)d_in[2];
  const float* asum   = (const float*)d_in[3];
  const int*   mask   = (const int*)  d_in[4];
  const float* cmt    = (const float*)d_in[5];
  const float* Wh     = (const float*)d_in[6];
  const float* bh     = (const float*)d_in[7];
  const float* Wc     = (const float*)d_in[8];
  const float* Wattn  = (const float*)d_in[9];
  const float* Walpha = (const float*)d_in[10];
  // d_in[11] = b_alpha: constant shift, cancels in softmax

  float* out_ctx   = (float*)d_out;              // [16,684]
  float* out_alpha = out_ctx + NB * NC;          // [16,4096] (epart0, then alpha)
  float* out_asum  = out_alpha + NB * HW;        // [16,4096]

  float* ws_q  = (float*)d_ws;                   // 16*512
  float* ws_M  = ws_q + NB * NA;                 // 512*132
  float* ws_e1 = ws_M + NA * 132;                // 16*4096 (epart, half 1)

  query_kernel<<<NB, 512, 0, stream>>>(hidden, Wh, bh, ws_q);
  m_kernel<<<NA, 192, 0, stream>>>(Wattn, Wc, ws_M);
  energy_kernel<<<NB * NH * 2, 256, 0, stream>>>(cft, cmt, asum, ws_q, ws_M, Walpha,
                                                 out_alpha, ws_e1);
  softmax_kernel<<<NB, 256, 0, stream>>>(out_alpha, ws_e1, mask, asum, out_asum);
  context_kernel<<<NB * NC, 256, 0, stream>>>(cnn, out_alpha, out_ctx);
}